// Round 4
// baseline (294.701 us; speedup 1.0000x reference)
//
#include <hip/hip_runtime.h>

// TransformerBlock on MI355X (gfx950).
// Fused in-proj (q,k from RoPE(x); v from x, written transposed), 16-head
// flash attention (D=64) using 32x32x16 MFMA computing S^T = K·Q^T so P lands
// in A-operand lane ownership (packed b64 P-writes, in-register row-sum l),
// out-proj (128x64 tiles), res+LN1, GeGLU, res+LN2.
// GEMMs: bf16 MFMA 16x16x32, BK=32, global_load_lds(16B).

typedef __bf16 bf16;
typedef bf16 bf16x8 __attribute__((ext_vector_type(8)));
typedef bf16 bf16x4 __attribute__((ext_vector_type(4)));
typedef float f32x4 __attribute__((ext_vector_type(4)));
typedef float f32x16 __attribute__((ext_vector_type(16)));

#define EMB 1024
#define SEQ 2048
#define NTOK 4096
#define NH 16
#define HD 64

__device__ __forceinline__ f32x4 mfma16(bf16x8 a, bf16x8 b, f32x4 c) {
  return __builtin_amdgcn_mfma_f32_16x16x32_bf16(a, b, c, 0, 0, 0);
}
__device__ __forceinline__ f32x16 mfma32(bf16x8 a, bf16x8 b, f32x16 c) {
  return __builtin_amdgcn_mfma_f32_32x32x16_bf16(a, b, c, 0, 0, 0);
}

__device__ __forceinline__ void gll16(const void* g, void* l) {
  __builtin_amdgcn_global_load_lds(
      (const __attribute__((address_space(1))) void*)g,
      (__attribute__((address_space(3))) void*)l, 16, 0, 0);
}

// ---------------- elementwise prep ----------------

__global__ __launch_bounds__(256) void rope_cast(
    const float* __restrict__ x, bf16* __restrict__ xb, bf16* __restrict__ qr) {
  int idx = blockIdx.x * 256 + threadIdx.x;   // 0 .. NTOK*512
  int row = idx >> 9;
  int i = idx & 511;
  int h = i >> 5, d2 = i & 31;
  int pos = row & (SEQ - 1);
  int c0 = h * HD + d2;
  size_t base = (size_t)row * EMB;
  float x0 = x[base + c0], x1 = x[base + c0 + 32];
  float invf = exp2f(-(float)d2 * 0.4152410118609203f);
  float ang = (float)pos * invf;
  float sn, cs;
  sincosf(ang, &sn, &cs);
  qr[base + c0] = (bf16)(x0 * cs - x1 * sn);
  qr[base + c0 + 32] = (bf16)(x1 * cs + x0 * sn);
  xb[base + c0] = (bf16)x0;
  xb[base + c0 + 32] = (bf16)x1;
}

__global__ __launch_bounds__(256) void cast_w(
    const float* __restrict__ w, bf16* __restrict__ o, int n) {
  int i = (blockIdx.x * 256 + threadIdx.x) * 4;
  if (i < n) {
    float4 f = *(const float4*)(w + i);
    o[i] = (bf16)f.x; o[i + 1] = (bf16)f.y;
    o[i + 2] = (bf16)f.z; o[i + 3] = (bf16)f.w;
  }
}

// ---------------- fused in-proj GEMM ----------------
__global__ __launch_bounds__(256) void gemm_in(
    const bf16* __restrict__ Aq, const bf16* __restrict__ Ax,
    const bf16* __restrict__ W, const float* __restrict__ bias,
    bf16* __restrict__ qk, bf16* __restrict__ vT) {
  __shared__ bf16 As[128 * 32];
  __shared__ bf16 Bs[128 * 32];
  const int tid = threadIdx.x, lane = tid & 63, wave = tid >> 6;
  const int quad = lane >> 4, l16 = lane & 15;
  const int m0 = blockIdx.y * 128, n0 = blockIdx.x * 128;
  const bf16* A = (n0 < 2048) ? Aq : Ax;
  const int K = 1024;
  const int wm = (wave >> 1) * 64, wn = (wave & 1) * 64;
  const int srow = wave * 32 + (lane >> 2);
  const int scol = (lane & 3) * 8;
  f32x4 acc[4][4] = {};
  for (int k0 = 0; k0 < K; k0 += 32) {
    __syncthreads();
    gll16(A + (size_t)(m0 + srow) * K + k0 + scol, As + wave * 1024);
    gll16(A + (size_t)(m0 + srow + 16) * K + k0 + scol, As + wave * 1024 + 512);
    gll16(W + (size_t)(n0 + srow) * K + k0 + scol, Bs + wave * 1024);
    gll16(W + (size_t)(n0 + srow + 16) * K + k0 + scol, Bs + wave * 1024 + 512);
    __syncthreads();
    bf16x8 af[4], bw[4];
#pragma unroll
    for (int t = 0; t < 4; ++t) {
      af[t] = *(const bf16x8*)(As + (wm + t * 16 + l16) * 32 + quad * 8);
      bw[t] = *(const bf16x8*)(Bs + (wn + t * 16 + l16) * 32 + quad * 8);
    }
#pragma unroll
    for (int mt = 0; mt < 4; ++mt)
#pragma unroll
      for (int nt = 0; nt < 4; ++nt)
        acc[mt][nt] = mfma16(af[mt], bw[nt], acc[mt][nt]);
  }
  if (n0 < 2048) {
#pragma unroll
    for (int mt = 0; mt < 4; ++mt)
      for (int nt = 0; nt < 4; ++nt) {
        const int n = n0 + wn + nt * 16 + l16;
        const float bv = bias[n];
#pragma unroll
        for (int r = 0; r < 4; ++r) {
          const int m = m0 + wm + mt * 16 + quad * 4 + r;
          qk[(size_t)m * 2048 + n] = (bf16)(acc[mt][nt][r] + bv);
        }
      }
  } else {
#pragma unroll
    for (int mt = 0; mt < 4; ++mt)
      for (int nt = 0; nt < 4; ++nt) {
        const int n = n0 + wn + nt * 16 + l16;
        const float bv = bias[n];
        const int m = m0 + wm + mt * 16 + quad * 4;
        const int bb = m >> 11, s = m & 2047;
        bf16x4 pk;
#pragma unroll
        for (int r = 0; r < 4; ++r) pk[r] = (bf16)(acc[mt][nt][r] + bv);
        *(bf16x4*)(vT + (((size_t)bb * 1024 + (n - 2048)) << 11) + s) = pk;
      }
  }
}

// ---------------- GEMM 128x128: C = A @ W^T + bias ----------------
__global__ __launch_bounds__(256) void gemm_bt(
    const bf16* __restrict__ A, const bf16* __restrict__ W,
    const float* __restrict__ bias,
    float* __restrict__ outF, bf16* __restrict__ outB,
    int M, int N, int K) {
  __shared__ bf16 As[128 * 32];
  __shared__ bf16 Bs[128 * 32];
  const int tid = threadIdx.x, lane = tid & 63, wave = tid >> 6;
  const int quad = lane >> 4, l16 = lane & 15;
  const int m0 = blockIdx.y * 128, n0 = blockIdx.x * 128;
  const int wm = (wave >> 1) * 64, wn = (wave & 1) * 64;
  const int srow = wave * 32 + (lane >> 2);
  const int scol = (lane & 3) * 8;
  f32x4 acc[4][4] = {};
  for (int k0 = 0; k0 < K; k0 += 32) {
    __syncthreads();
    gll16(A + (size_t)(m0 + srow) * K + k0 + scol, As + wave * 1024);
    gll16(A + (size_t)(m0 + srow + 16) * K + k0 + scol, As + wave * 1024 + 512);
    gll16(W + (size_t)(n0 + srow) * K + k0 + scol, Bs + wave * 1024);
    gll16(W + (size_t)(n0 + srow + 16) * K + k0 + scol, Bs + wave * 1024 + 512);
    __syncthreads();
    bf16x8 af[4], bw[4];
#pragma unroll
    for (int t = 0; t < 4; ++t) {
      af[t] = *(const bf16x8*)(As + (wm + t * 16 + l16) * 32 + quad * 8);
      bw[t] = *(const bf16x8*)(Bs + (wn + t * 16 + l16) * 32 + quad * 8);
    }
#pragma unroll
    for (int mt = 0; mt < 4; ++mt)
#pragma unroll
      for (int nt = 0; nt < 4; ++nt)
        acc[mt][nt] = mfma16(af[mt], bw[nt], acc[mt][nt]);
  }
#pragma unroll
  for (int mt = 0; mt < 4; ++mt)
    for (int nt = 0; nt < 4; ++nt) {
      const int n = n0 + wn + nt * 16 + l16;
      const float bv = bias ? bias[n] : 0.0f;
#pragma unroll
      for (int r = 0; r < 4; ++r) {
        const int m = m0 + wm + mt * 16 + quad * 4 + r;
        const float v = acc[mt][nt][r] + bv;
        if (outF) outF[(size_t)m * N + n] = v;
        if (outB) outB[(size_t)m * N + n] = (bf16)v;
      }
    }
}

// ---------------- GEMM 128x64 tiles ----------------
__global__ __launch_bounds__(256) void gemm_bt64(
    const bf16* __restrict__ A, const bf16* __restrict__ W,
    const float* __restrict__ bias, float* __restrict__ outF,
    int M, int N, int K) {
  __shared__ bf16 As[128 * 32];
  __shared__ bf16 Bs[64 * 32];
  const int tid = threadIdx.x, lane = tid & 63, wave = tid >> 6;
  const int quad = lane >> 4, l16 = lane & 15;
  const int m0 = blockIdx.y * 128, n0 = blockIdx.x * 64;
  const int wm = (wave >> 1) * 64, wn = (wave & 1) * 32;
  const int srow = wave * 32 + (lane >> 2);
  const int srowB = wave * 16 + (lane >> 2);
  const int scol = (lane & 3) * 8;
  f32x4 acc[4][2] = {};
  for (int k0 = 0; k0 < K; k0 += 32) {
    __syncthreads();
    gll16(A + (size_t)(m0 + srow) * K + k0 + scol, As + wave * 1024);
    gll16(A + (size_t)(m0 + srow + 16) * K + k0 + scol, As + wave * 1024 + 512);
    gll16(W + (size_t)(n0 + srowB) * K + k0 + scol, Bs + wave * 512);
    __syncthreads();
    bf16x8 af[4], bw[2];
#pragma unroll
    for (int t = 0; t < 4; ++t)
      af[t] = *(const bf16x8*)(As + (wm + t * 16 + l16) * 32 + quad * 8);
#pragma unroll
    for (int t = 0; t < 2; ++t)
      bw[t] = *(const bf16x8*)(Bs + (wn + t * 16 + l16) * 32 + quad * 8);
#pragma unroll
    for (int mt = 0; mt < 4; ++mt)
#pragma unroll
      for (int nt = 0; nt < 2; ++nt)
        acc[mt][nt] = mfma16(af[mt], bw[nt], acc[mt][nt]);
  }
#pragma unroll
  for (int mt = 0; mt < 4; ++mt)
    for (int nt = 0; nt < 2; ++nt) {
      const int n = n0 + wn + nt * 16 + l16;
      const float bv = bias[n];
#pragma unroll
      for (int r = 0; r < 4; ++r) {
        const int m = m0 + wm + mt * 16 + quad * 4 + r;
        outF[(size_t)m * N + n] = acc[mt][nt][r] + bv;
      }
    }
}

// ---------------- flash attention v4: 32x32x16 MFMA, S^T form ----------------
// block = (128 q-rows, head, batch), 4 waves x 32 q-rows. Per 64-key tile:
// S^T = K·Q^T (A=K frag from LDS, B=Q frag in regs). C-layout: col=lane&31=q,
// row=key=(r&3)+8*(r>>2)+4*hi -> reg-quads hold 4 consecutive keys => packed
// b64 P-writes into LDS [q][key]. Row-sum l accumulates in-register per lane
// (lane owns one q-column), one shfl_xor(32) at the end. PV: A=P, B=V from
// LDS [d][key]. All LDS 16B-chunk XOR-swizzled.
__global__ __launch_bounds__(256) void attn4(
    const bf16* __restrict__ QK, const bf16* __restrict__ VT,
    bf16* __restrict__ ctx) {
  __shared__ __align__(16) bf16 Ks[64 * 64];
  __shared__ __align__(16) bf16 Vs[64 * 64];
  __shared__ __align__(16) bf16 Ps[4 * 32 * 64];
  __shared__ float Linv[4][32];
  const int tid = threadIdx.x, lane = tid & 63, wave = tid >> 6;
  const int hi = lane >> 5, l31 = lane & 31, l7 = lane & 7;
  const int qt = blockIdx.x, h = blockIdx.y, b = blockIdx.z;

  // Q B-frags (B[k=d][n=q]: lane n=q=l31, k=d=t*16+hi*8+j), scaled by 0.125
  bf16x8 qf[4];
  {
    const int qrow = qt * 128 + wave * 32 + l31;
    const bf16* qp = QK + (size_t)(b * SEQ + qrow) * 2048 + h * HD + hi * 8;
#pragma unroll
    for (int t = 0; t < 4; ++t) {
      bf16x8 v = *(const bf16x8*)(qp + t * 16);
#pragma unroll
      for (int j = 0; j < 8; ++j) v[j] = (bf16)((float)v[j] * 0.125f);
      qf[t] = v;
    }
  }
  f32x16 o0 = {}, o1 = {};
  float lpart = 0.0f;

  const bf16* kg = QK + (size_t)(b * SEQ) * 2048 + 1024 + h * HD;
  const bf16* vg = VT + ((size_t)(b * NH + h) * HD) * 2048;
  bf16* pw = Ps + wave * 2048;

  for (int kb = 0; kb < SEQ; kb += 64) {
    __syncthreads();
#pragma unroll
    for (int p = 0; p < 2; ++p) {   // stage K[key][d] and V^T[d][key], swizzled
      const int c = p * 256 + tid;
      const int row = c >> 3, c16 = c & 7;
      const int sw = row * 64 + ((c16 ^ (row & 7)) * 8);
      *(bf16x8*)(Ks + sw) = *(const bf16x8*)(kg + (size_t)(kb + row) * 2048 + c16 * 8);
      *(bf16x8*)(Vs + sw) = *(const bf16x8*)(vg + (size_t)row * 2048 + kb + c16 * 8);
    }
    __syncthreads();
    // S^T[key][q], two 32-key chunks
    f32x16 s0 = {}, s1 = {};
#pragma unroll
    for (int t = 0; t < 4; ++t) {
      const int swc = ((t * 2 + hi) ^ l7) * 8;
      bf16x8 k0 = *(const bf16x8*)(Ks + l31 * 64 + swc);
      bf16x8 k1 = *(const bf16x8*)(Ks + (32 + l31) * 64 + swc);
      s0 = mfma32(k0, qf[t], s0);
      s1 = mfma32(k1, qf[t], s1);
    }
    // exp + packed P write (keys kc*32 + g*8 + hi*4 + 0..3 at row q=l31)
#pragma unroll
    for (int kc = 0; kc < 2; ++kc) {
      const f32x16& sv = kc ? s1 : s0;
#pragma unroll
      for (int g = 0; g < 4; ++g) {
        bf16x4 pk;
#pragma unroll
        for (int j = 0; j < 4; ++j) {
          float e = __expf(sv[g * 4 + j]);
          lpart += e;
          pk[j] = (bf16)e;
        }
        *(bf16x4*)(pw + l31 * 64 + (((kc * 4 + g) ^ l7) * 8) + hi * 4) = pk;
      }
    }
    // O += P·V  (A=P[q][key], B=V[key][d] from Vs[d][key])
#pragma unroll
    for (int t2 = 0; t2 < 4; ++t2) {
      const int swc = ((t2 * 2 + hi) ^ l7) * 8;
      bf16x8 pf = *(const bf16x8*)(pw + l31 * 64 + swc);
      bf16x8 v0 = *(const bf16x8*)(Vs + l31 * 64 + swc);
      bf16x8 v1 = *(const bf16x8*)(Vs + (32 + l31) * 64 + swc);
      o0 = mfma32(pf, v0, o0);
      o1 = mfma32(pf, v1, o1);
    }
  }
  // epilogue
  float ltot = lpart + __shfl_xor(lpart, 32, 64);
  if (lane < 32) Linv[wave][lane] = 1.0f / ltot;
#pragma unroll
  for (int r = 0; r < 16; ++r) {
    const int qloc = (r & 3) + 8 * (r >> 2) + 4 * hi;
    const float inv = Linv[wave][qloc];
    const int qrow = qt * 128 + wave * 32 + qloc;
    bf16* cp = ctx + (size_t)(b * SEQ + qrow) * EMB + h * HD;
    cp[l31] = (bf16)(o0[r] * inv);
    cp[32 + l31] = (bf16)(o1[r] * inv);
  }
}

// ---------------- residual + LayerNorm ----------------
__global__ __launch_bounds__(256) void ln1_k(
    const float* __restrict__ x, const float* __restrict__ ao,
    const float* __restrict__ g, const float* __restrict__ bta,
    float* __restrict__ hF, bf16* __restrict__ hB) {
  int row = blockIdx.x, tid = threadIdx.x;
  const float* xr = x + (size_t)row * EMB;
  const float* ar = ao + (size_t)row * EMB;
  float v[4], s = 0.0f, s2 = 0.0f;
#pragma unroll
  for (int i = 0; i < 4; ++i) {
    float t = xr[tid + i * 256] + ar[tid + i * 256];
    v[i] = t; s += t; s2 += t * t;
  }
#pragma unroll
  for (int off = 1; off < 64; off <<= 1) {
    s += __shfl_xor(s, off, 64);
    s2 += __shfl_xor(s2, off, 64);
  }
  __shared__ float red[8];
  int wave = tid >> 6, lane = tid & 63;
  if (lane == 0) { red[wave] = s; red[4 + wave] = s2; }
  __syncthreads();
  s = red[0] + red[1] + red[2] + red[3];
  s2 = red[4] + red[5] + red[6] + red[7];
  float mean = s * (1.0f / EMB);
  float var = s2 * (1.0f / EMB) - mean * mean;
  float inv = rsqrtf(var + 1e-5f);
#pragma unroll
  for (int i = 0; i < 4; ++i) {
    int c = tid + i * 256;
    float t = (v[i] - mean) * inv * g[c] + bta[c];
    hF[(size_t)row * EMB + c] = t;
    hB[(size_t)row * EMB + c] = (bf16)t;
  }
}

__global__ __launch_bounds__(256) void geglu_ln2(
    const float* __restrict__ h, const bf16* __restrict__ proj,
    const float* __restrict__ g, const float* __restrict__ bta,
    float* __restrict__ out) {
  int row = blockIdx.x, tid = threadIdx.x;
  const float* hr = h + (size_t)row * EMB;
  const bf16* pr = proj + (size_t)row * 2048;
  float v[4], s = 0.0f, s2 = 0.0f;
#pragma unroll
  for (int i = 0; i < 4; ++i) {
    int c = tid + i * 256;
    float val = (float)pr[c];
    float gate = (float)pr[1024 + c];
    float ge = 0.5f * gate * (1.0f + erff(gate * 0.70710678f));
    float t = hr[c] + val * ge;
    v[i] = t; s += t; s2 += t * t;
  }
#pragma unroll
  for (int off = 1; off < 64; off <<= 1) {
    s += __shfl_xor(s, off, 64);
    s2 += __shfl_xor(s2, off, 64);
  }
  __shared__ float red[8];
  int wave = tid >> 6, lane = tid & 63;
  if (lane == 0) { red[wave] = s; red[4 + wave] = s2; }
  __syncthreads();
  s = red[0] + red[1] + red[2] + red[3];
  s2 = red[4] + red[5] + red[6] + red[7];
  float mean = s * (1.0f / EMB);
  float var = s2 * (1.0f / EMB) - mean * mean;
  float inv = rsqrtf(var + 1e-5f);
#pragma unroll
  for (int i = 0; i < 4; ++i) {
    int c = tid + i * 256;
    out[(size_t)row * EMB + c] = (v[i] - mean) * inv * g[c] + bta[c];
  }
}

extern "C" void kernel_launch(void* const* d_in, const int* in_sizes, int n_in,
                              void* d_out, int out_size, void* d_ws, size_t ws_size,
                              hipStream_t stream) {
  const float* x = (const float*)d_in[0];
  const float* inW = (const float*)d_in[1];
  const float* inB = (const float*)d_in[2];
  const float* outW = (const float*)d_in[3];
  const float* opB = (const float*)d_in[4];
  const float* ggW = (const float*)d_in[5];
  const float* ggB = (const float*)d_in[6];
  const float* g1 = (const float*)d_in[7];
  const float* b1 = (const float*)d_in[8];
  const float* g2 = (const float*)d_in[9];
  const float* b2 = (const float*)d_in[10];
  float* out = (float*)d_out;
  char* ws = (char*)d_ws;
  const size_t MB = 1ull << 20;
  bf16* xb = (bf16*)(ws);              // 8 MB
  bf16* qr = (bf16*)(ws + 8 * MB);     // 8 MB, dead after in-proj
  bf16* ctx = (bf16*)(ws + 8 * MB);    // overlays qr (attn output)
  bf16* wI = (bf16*)(ws + 16 * MB);    // 6 MB
  bf16* wO = (bf16*)(ws + 22 * MB);    // 2 MB
  bf16* wG = (bf16*)(ws + 24 * MB);    // 4 MB
  bf16* qk = (bf16*)(ws + 28 * MB);    // 16 MB, dead after attn
  bf16* projB = (bf16*)(ws + 28 * MB); // overlays qk
  bf16* vbT = (bf16*)(ws + 44 * MB);   // 8 MB V^T, dead after attn
  float* ao = (float*)(ws + 44 * MB);  // 16 MB f32, overlays vbT
  bf16* hB = (bf16*)(ws + 60 * MB);    // 8 MB

  rope_cast<<<NTOK * 512 / 256, 256, 0, stream>>>(x, xb, qr);
  cast_w<<<(3072 * 1024 / 4) / 256, 256, 0, stream>>>(inW, wI, 3072 * 1024);
  cast_w<<<(1024 * 1024 / 4) / 256, 256, 0, stream>>>(outW, wO, 1024 * 1024);
  cast_w<<<(2048 * 1024 / 4) / 256, 256, 0, stream>>>(ggW, wG, 2048 * 1024);
  gemm_in<<<dim3(24, 32), 256, 0, stream>>>(qr, xb, wI, inB, qk, vbT);
  attn4<<<dim3(16, 16, 2), 256, 0, stream>>>(qk, vbT, ctx);
  gemm_bt64<<<dim3(16, 32), 256, 0, stream>>>(ctx, wO, opB, ao,
                                              NTOK, 1024, 1024);
  ln1_k<<<NTOK, 256, 0, stream>>>(x, ao, g1, b1, ao, hB);
  gemm_bt<<<dim3(16, 32), 256, 0, stream>>>(hB, wG, ggB, nullptr, projB,
                                            NTOK, 2048, 1024);
  geglu_ln2<<<NTOK, 256, 0, stream>>>(ao, projB, g2, b2, out);
}

// Round 5
// 277.350 us; speedup vs baseline: 1.0626x; 1.0626x over previous
//
#include <hip/hip_runtime.h>

// TransformerBlock on MI355X (gfx950).
// Fused in-proj (q,k from RoPE(x); v from x, written transposed), 16-head
// flash attention (D=64): 32x32x16 MFMA computing S^T = K·Q^T; P never touches
// LDS (quad-exchange via shfl_xor(32) maps C-layout -> A-operand layout);
// K/V tiles register-prefetched ahead of the staging barrier. Then out-proj
// (128x64 tiles), res+LN1, GeGLU, res+LN2.
// GEMMs: bf16 MFMA 16x16x32, BK=32, global_load_lds(16B).

typedef __bf16 bf16;
typedef bf16 bf16x8 __attribute__((ext_vector_type(8)));
typedef bf16 bf16x4 __attribute__((ext_vector_type(4)));
typedef float f32x4 __attribute__((ext_vector_type(4)));
typedef float f32x16 __attribute__((ext_vector_type(16)));

#define EMB 1024
#define SEQ 2048
#define NTOK 4096
#define NH 16
#define HD 64

__device__ __forceinline__ f32x4 mfma16(bf16x8 a, bf16x8 b, f32x4 c) {
  return __builtin_amdgcn_mfma_f32_16x16x32_bf16(a, b, c, 0, 0, 0);
}
__device__ __forceinline__ f32x16 mfma32(bf16x8 a, bf16x8 b, f32x16 c) {
  return __builtin_amdgcn_mfma_f32_32x32x16_bf16(a, b, c, 0, 0, 0);
}

__device__ __forceinline__ void gll16(const void* g, void* l) {
  __builtin_amdgcn_global_load_lds(
      (const __attribute__((address_space(1))) void*)g,
      (__attribute__((address_space(3))) void*)l, 16, 0, 0);
}

__device__ __forceinline__ unsigned pk2(float a, float b) {
  union { bf16 h[2]; unsigned u; } t;
  t.h[0] = (bf16)a; t.h[1] = (bf16)b;
  return t.u;
}

// ---------------- elementwise prep ----------------

__global__ __launch_bounds__(256) void rope_cast(
    const float* __restrict__ x, bf16* __restrict__ xb, bf16* __restrict__ qr) {
  int idx = blockIdx.x * 256 + threadIdx.x;   // 0 .. NTOK*512
  int row = idx >> 9;
  int i = idx & 511;
  int h = i >> 5, d2 = i & 31;
  int pos = row & (SEQ - 1);
  int c0 = h * HD + d2;
  size_t base = (size_t)row * EMB;
  float x0 = x[base + c0], x1 = x[base + c0 + 32];
  float invf = exp2f(-(float)d2 * 0.4152410118609203f);
  float ang = (float)pos * invf;
  float sn, cs;
  sincosf(ang, &sn, &cs);
  qr[base + c0] = (bf16)(x0 * cs - x1 * sn);
  qr[base + c0 + 32] = (bf16)(x1 * cs + x0 * sn);
  xb[base + c0] = (bf16)x0;
  xb[base + c0 + 32] = (bf16)x1;
}

__global__ __launch_bounds__(256) void cast_w(
    const float* __restrict__ w, bf16* __restrict__ o, int n) {
  int i = (blockIdx.x * 256 + threadIdx.x) * 4;
  if (i < n) {
    float4 f = *(const float4*)(w + i);
    o[i] = (bf16)f.x; o[i + 1] = (bf16)f.y;
    o[i + 2] = (bf16)f.z; o[i + 3] = (bf16)f.w;
  }
}

// ---------------- fused in-proj GEMM ----------------
__global__ __launch_bounds__(256) void gemm_in(
    const bf16* __restrict__ Aq, const bf16* __restrict__ Ax,
    const bf16* __restrict__ W, const float* __restrict__ bias,
    bf16* __restrict__ qk, bf16* __restrict__ vT) {
  __shared__ bf16 As[128 * 32];
  __shared__ bf16 Bs[128 * 32];
  const int tid = threadIdx.x, lane = tid & 63, wave = tid >> 6;
  const int quad = lane >> 4, l16 = lane & 15;
  const int m0 = blockIdx.y * 128, n0 = blockIdx.x * 128;
  const bf16* A = (n0 < 2048) ? Aq : Ax;
  const int K = 1024;
  const int wm = (wave >> 1) * 64, wn = (wave & 1) * 64;
  const int srow = wave * 32 + (lane >> 2);
  const int scol = (lane & 3) * 8;
  f32x4 acc[4][4] = {};
  for (int k0 = 0; k0 < K; k0 += 32) {
    __syncthreads();
    gll16(A + (size_t)(m0 + srow) * K + k0 + scol, As + wave * 1024);
    gll16(A + (size_t)(m0 + srow + 16) * K + k0 + scol, As + wave * 1024 + 512);
    gll16(W + (size_t)(n0 + srow) * K + k0 + scol, Bs + wave * 1024);
    gll16(W + (size_t)(n0 + srow + 16) * K + k0 + scol, Bs + wave * 1024 + 512);
    __syncthreads();
    bf16x8 af[4], bw[4];
#pragma unroll
    for (int t = 0; t < 4; ++t) {
      af[t] = *(const bf16x8*)(As + (wm + t * 16 + l16) * 32 + quad * 8);
      bw[t] = *(const bf16x8*)(Bs + (wn + t * 16 + l16) * 32 + quad * 8);
    }
#pragma unroll
    for (int mt = 0; mt < 4; ++mt)
#pragma unroll
      for (int nt = 0; nt < 4; ++nt)
        acc[mt][nt] = mfma16(af[mt], bw[nt], acc[mt][nt]);
  }
  if (n0 < 2048) {
#pragma unroll
    for (int mt = 0; mt < 4; ++mt)
      for (int nt = 0; nt < 4; ++nt) {
        const int n = n0 + wn + nt * 16 + l16;
        const float bv = bias[n];
#pragma unroll
        for (int r = 0; r < 4; ++r) {
          const int m = m0 + wm + mt * 16 + quad * 4 + r;
          qk[(size_t)m * 2048 + n] = (bf16)(acc[mt][nt][r] + bv);
        }
      }
  } else {
#pragma unroll
    for (int mt = 0; mt < 4; ++mt)
      for (int nt = 0; nt < 4; ++nt) {
        const int n = n0 + wn + nt * 16 + l16;
        const float bv = bias[n];
        const int m = m0 + wm + mt * 16 + quad * 4;
        const int bb = m >> 11, s = m & 2047;
        bf16x4 pkv;
#pragma unroll
        for (int r = 0; r < 4; ++r) pkv[r] = (bf16)(acc[mt][nt][r] + bv);
        *(bf16x4*)(vT + (((size_t)bb * 1024 + (n - 2048)) << 11) + s) = pkv;
      }
  }
}

// ---------------- GEMM 128x128: C = A @ W^T + bias ----------------
__global__ __launch_bounds__(256) void gemm_bt(
    const bf16* __restrict__ A, const bf16* __restrict__ W,
    const float* __restrict__ bias,
    float* __restrict__ outF, bf16* __restrict__ outB,
    int M, int N, int K) {
  __shared__ bf16 As[128 * 32];
  __shared__ bf16 Bs[128 * 32];
  const int tid = threadIdx.x, lane = tid & 63, wave = tid >> 6;
  const int quad = lane >> 4, l16 = lane & 15;
  const int m0 = blockIdx.y * 128, n0 = blockIdx.x * 128;
  const int wm = (wave >> 1) * 64, wn = (wave & 1) * 64;
  const int srow = wave * 32 + (lane >> 2);
  const int scol = (lane & 3) * 8;
  f32x4 acc[4][4] = {};
  for (int k0 = 0; k0 < K; k0 += 32) {
    __syncthreads();
    gll16(A + (size_t)(m0 + srow) * K + k0 + scol, As + wave * 1024);
    gll16(A + (size_t)(m0 + srow + 16) * K + k0 + scol, As + wave * 1024 + 512);
    gll16(W + (size_t)(n0 + srow) * K + k0 + scol, Bs + wave * 1024);
    gll16(W + (size_t)(n0 + srow + 16) * K + k0 + scol, Bs + wave * 1024 + 512);
    __syncthreads();
    bf16x8 af[4], bw[4];
#pragma unroll
    for (int t = 0; t < 4; ++t) {
      af[t] = *(const bf16x8*)(As + (wm + t * 16 + l16) * 32 + quad * 8);
      bw[t] = *(const bf16x8*)(Bs + (wn + t * 16 + l16) * 32 + quad * 8);
    }
#pragma unroll
    for (int mt = 0; mt < 4; ++mt)
#pragma unroll
      for (int nt = 0; nt < 4; ++nt)
        acc[mt][nt] = mfma16(af[mt], bw[nt], acc[mt][nt]);
  }
#pragma unroll
  for (int mt = 0; mt < 4; ++mt)
    for (int nt = 0; nt < 4; ++nt) {
      const int n = n0 + wn + nt * 16 + l16;
      const float bv = bias ? bias[n] : 0.0f;
#pragma unroll
      for (int r = 0; r < 4; ++r) {
        const int m = m0 + wm + mt * 16 + quad * 4 + r;
        const float v = acc[mt][nt][r] + bv;
        if (outF) outF[(size_t)m * N + n] = v;
        if (outB) outB[(size_t)m * N + n] = (bf16)v;
      }
    }
}

// ---------------- GEMM 128x64 tiles ----------------
__global__ __launch_bounds__(256) void gemm_bt64(
    const bf16* __restrict__ A, const bf16* __restrict__ W,
    const float* __restrict__ bias, float* __restrict__ outF,
    int M, int N, int K) {
  __shared__ bf16 As[128 * 32];
  __shared__ bf16 Bs[64 * 32];
  const int tid = threadIdx.x, lane = tid & 63, wave = tid >> 6;
  const int quad = lane >> 4, l16 = lane & 15;
  const int m0 = blockIdx.y * 128, n0 = blockIdx.x * 64;
  const int wm = (wave >> 1) * 64, wn = (wave & 1) * 32;
  const int srow = wave * 32 + (lane >> 2);
  const int srowB = wave * 16 + (lane >> 2);
  const int scol = (lane & 3) * 8;
  f32x4 acc[4][2] = {};
  for (int k0 = 0; k0 < K; k0 += 32) {
    __syncthreads();
    gll16(A + (size_t)(m0 + srow) * K + k0 + scol, As + wave * 1024);
    gll16(A + (size_t)(m0 + srow + 16) * K + k0 + scol, As + wave * 1024 + 512);
    gll16(W + (size_t)(n0 + srowB) * K + k0 + scol, Bs + wave * 512);
    __syncthreads();
    bf16x8 af[4], bw[2];
#pragma unroll
    for (int t = 0; t < 4; ++t)
      af[t] = *(const bf16x8*)(As + (wm + t * 16 + l16) * 32 + quad * 8);
#pragma unroll
    for (int t = 0; t < 2; ++t)
      bw[t] = *(const bf16x8*)(Bs + (wn + t * 16 + l16) * 32 + quad * 8);
#pragma unroll
    for (int mt = 0; mt < 4; ++mt)
#pragma unroll
      for (int nt = 0; nt < 2; ++nt)
        acc[mt][nt] = mfma16(af[mt], bw[nt], acc[mt][nt]);
  }
#pragma unroll
  for (int mt = 0; mt < 4; ++mt)
    for (int nt = 0; nt < 2; ++nt) {
      const int n = n0 + wn + nt * 16 + l16;
      const float bv = bias[n];
#pragma unroll
      for (int r = 0; r < 4; ++r) {
        const int m = m0 + wm + mt * 16 + quad * 4 + r;
        outF[(size_t)m * N + n] = acc[mt][nt][r] + bv;
      }
    }
}

// ---------------- flash attention v6 ----------------
// block = (128 q-rows, head, batch), 4 waves x 32 q-rows, 32x32x16 MFMA.
// S^T = K·Q^T; C-layout lane owns col q=l31, reg-quads = 4 consecutive keys.
// P -> PV A-fragment via shfl_xor(32) quad exchange (zero LDS for P).
// K/V tiles prefetched into registers one tile ahead of the staging barrier.
__global__ __launch_bounds__(256) void attn6(
    const bf16* __restrict__ QK, const bf16* __restrict__ VT,
    bf16* __restrict__ ctx) {
  __shared__ __align__(16) bf16 Ks[64 * 64];
  __shared__ __align__(16) bf16 Vs[64 * 64];
  __shared__ float Linv[4][32];
  const int tid = threadIdx.x, lane = tid & 63, wave = tid >> 6;
  const int hi = lane >> 5, l31 = lane & 31, l7 = lane & 7;
  const int qt = blockIdx.x, h = blockIdx.y, b = blockIdx.z;

  // Q B-frags (B[k=d][n=q]: lane n=q=l31, d = t*16 + hi*8 + j), scaled 0.125
  bf16x8 qf[4];
  {
    const int qrow = qt * 128 + wave * 32 + l31;
    const bf16* qp = QK + (size_t)(b * SEQ + qrow) * 2048 + h * HD + hi * 8;
#pragma unroll
    for (int t = 0; t < 4; ++t) {
      bf16x8 v = *(const bf16x8*)(qp + t * 16);
#pragma unroll
      for (int j = 0; j < 8; ++j) v[j] = (bf16)((float)v[j] * 0.125f);
      qf[t] = v;
    }
  }
  f32x16 o0 = {}, o1 = {};
  float lpart = 0.0f;

  const int srow = tid >> 3;   // 0..31 staging row
  const int sc16 = tid & 7;    // 16B chunk
  const bf16* kg = QK + (size_t)(b * SEQ) * 2048 + 1024 + h * HD + sc16 * 8;
  const bf16* vg = VT + ((size_t)(b * NH + h) * HD) * 2048 + sc16 * 8;

  // prefetch tile 0
  bf16x8 kcur[2], vcur[2];
#pragma unroll
  for (int p = 0; p < 2; ++p) {
    const int row = p * 32 + srow;
    kcur[p] = *(const bf16x8*)(kg + (size_t)row * 2048);
    vcur[p] = *(const bf16x8*)(vg + (size_t)row * 2048);
  }

  for (int kb = 0; kb < SEQ; kb += 64) {
    __syncthreads();
#pragma unroll
    for (int p = 0; p < 2; ++p) {
      const int row = p * 32 + srow;
      const int sw = row * 64 + ((sc16 ^ (row & 7)) * 8);
      *(bf16x8*)(Ks + sw) = kcur[p];
      *(bf16x8*)(Vs + sw) = vcur[p];
    }
    __syncthreads();
    if (kb + 64 < SEQ) {   // prefetch next tile; latency hidden under compute
#pragma unroll
      for (int p = 0; p < 2; ++p) {
        const int row = p * 32 + srow;
        kcur[p] = *(const bf16x8*)(kg + (size_t)(kb + 64 + row) * 2048);
        vcur[p] = *(const bf16x8*)(vg + (size_t)row * 2048 + kb + 64);
      }
    }
    // S^T[key][q]: keys l31 (s0) and 32+l31 (s1)
    f32x16 s0 = {}, s1 = {};
#pragma unroll
    for (int t = 0; t < 4; ++t) {
      const int swc = ((t * 2 + hi) ^ l7) * 8;
      bf16x8 k0 = *(const bf16x8*)(Ks + l31 * 64 + swc);
      bf16x8 k1 = *(const bf16x8*)(Ks + (32 + l31) * 64 + swc);
      s0 = mfma32(k0, qf[t], s0);
      s1 = mfma32(k1, qf[t], s1);
    }
    // exp -> packed bf16 quads; u[2g],u[2g+1] = quad g (keys 8g+4hi+0..3 [+32])
    unsigned u[16];
#pragma unroll
    for (int g = 0; g < 8; ++g) {
      const int base = (g & 3) * 4;
      float e0, e1, e2, e3;
      if (g < 4) {
        e0 = __expf(s0[base]); e1 = __expf(s0[base + 1]);
        e2 = __expf(s0[base + 2]); e3 = __expf(s0[base + 3]);
      } else {
        e0 = __expf(s1[base]); e1 = __expf(s1[base + 1]);
        e2 = __expf(s1[base + 2]); e3 = __expf(s1[base + 3]);
      }
      lpart += (e0 + e1) + (e2 + e3);
      u[g * 2] = pk2(e0, e1);
      u[g * 2 + 1] = pk2(e2, e3);
    }
    // PV: 4 key-chunks of 16; A-frag assembled via quad exchange shfl_xor(32)
#pragma unroll
    for (int kk = 0; kk < 4; ++kk) {
      const int ub = (kk >> 1) * 8 + (kk & 1) * 4;
      unsigned sx = hi ? u[ub] : u[ub + 2];
      unsigned sy = hi ? u[ub + 1] : u[ub + 3];
      unsigned rx = (unsigned)__shfl_xor((int)sx, 32, 64);
      unsigned ry = (unsigned)__shfl_xor((int)sy, 32, 64);
      union { unsigned w[4]; bf16x8 v; } fw;
      fw.w[0] = hi ? rx : u[ub];
      fw.w[1] = hi ? ry : u[ub + 1];
      fw.w[2] = hi ? u[ub + 2] : rx;
      fw.w[3] = hi ? u[ub + 3] : ry;
      const int swc = ((kk * 2 + hi) ^ l7) * 8;
      bf16x8 v0 = *(const bf16x8*)(Vs + l31 * 64 + swc);
      bf16x8 v1 = *(const bf16x8*)(Vs + (32 + l31) * 64 + swc);
      o0 = mfma32(fw.v, v0, o0);
      o1 = mfma32(fw.v, v1, o1);
    }
  }
  // epilogue
  float ltot = lpart + __shfl_xor(lpart, 32, 64);
  if (lane < 32) Linv[wave][lane] = 1.0f / ltot;
#pragma unroll
  for (int r = 0; r < 16; ++r) {
    const int qloc = (r & 3) + 8 * (r >> 2) + 4 * hi;
    const float inv = Linv[wave][qloc];
    const int qrow = qt * 128 + wave * 32 + qloc;
    bf16* cp = ctx + (size_t)(b * SEQ + qrow) * EMB + h * HD;
    cp[l31] = (bf16)(o0[r] * inv);
    cp[32 + l31] = (bf16)(o1[r] * inv);
  }
}

// ---------------- residual + LayerNorm ----------------
__global__ __launch_bounds__(256) void ln1_k(
    const float* __restrict__ x, const float* __restrict__ ao,
    const float* __restrict__ g, const float* __restrict__ bta,
    float* __restrict__ hF, bf16* __restrict__ hB) {
  int row = blockIdx.x, tid = threadIdx.x;
  const float* xr = x + (size_t)row * EMB;
  const float* ar = ao + (size_t)row * EMB;
  float v[4], s = 0.0f, s2 = 0.0f;
#pragma unroll
  for (int i = 0; i < 4; ++i) {
    float t = xr[tid + i * 256] + ar[tid + i * 256];
    v[i] = t; s += t; s2 += t * t;
  }
#pragma unroll
  for (int off = 1; off < 64; off <<= 1) {
    s += __shfl_xor(s, off, 64);
    s2 += __shfl_xor(s2, off, 64);
  }
  __shared__ float red[8];
  int wave = tid >> 6, lane = tid & 63;
  if (lane == 0) { red[wave] = s; red[4 + wave] = s2; }
  __syncthreads();
  s = red[0] + red[1] + red[2] + red[3];
  s2 = red[4] + red[5] + red[6] + red[7];
  float mean = s * (1.0f / EMB);
  float var = s2 * (1.0f / EMB) - mean * mean;
  float inv = rsqrtf(var + 1e-5f);
#pragma unroll
  for (int i = 0; i < 4; ++i) {
    int c = tid + i * 256;
    float t = (v[i] - mean) * inv * g[c] + bta[c];
    hF[(size_t)row * EMB + c] = t;
    hB[(size_t)row * EMB + c] = (bf16)t;
  }
}

__global__ __launch_bounds__(256) void geglu_ln2(
    const float* __restrict__ h, const bf16* __restrict__ proj,
    const float* __restrict__ g, const float* __restrict__ bta,
    float* __restrict__ out) {
  int row = blockIdx.x, tid = threadIdx.x;
  const float* hr = h + (size_t)row * EMB;
  const bf16* pr = proj + (size_t)row * 2048;
  float v[4], s = 0.0f, s2 = 0.0f;
#pragma unroll
  for (int i = 0; i < 4; ++i) {
    int c = tid + i * 256;
    float val = (float)pr[c];
    float gate = (float)pr[1024 + c];
    float ge = 0.5f * gate * (1.0f + erff(gate * 0.70710678f));
    float t = hr[c] + val * ge;
    v[i] = t; s += t; s2 += t * t;
  }
#pragma unroll
  for (int off = 1; off < 64; off <<= 1) {
    s += __shfl_xor(s, off, 64);
    s2 += __shfl_xor(s2, off, 64);
  }
  __shared__ float red[8];
  int wave = tid >> 6, lane = tid & 63;
  if (lane == 0) { red[wave] = s; red[4 + wave] = s2; }
  __syncthreads();
  s = red[0] + red[1] + red[2] + red[3];
  s2 = red[4] + red[5] + red[6] + red[7];
  float mean = s * (1.0f / EMB);
  float var = s2 * (1.0f / EMB) - mean * mean;
  float inv = rsqrtf(var + 1e-5f);
#pragma unroll
  for (int i = 0; i < 4; ++i) {
    int c = tid + i * 256;
    out[(size_t)row * EMB + c] = (v[i] - mean) * inv * g[c] + bta[c];
  }
}

extern "C" void kernel_launch(void* const* d_in, const int* in_sizes, int n_in,
                              void* d_out, int out_size, void* d_ws, size_t ws_size,
                              hipStream_t stream) {
  const float* x = (const float*)d_in[0];
  const float* inW = (const float*)d_in[1];
  const float* inB = (const float*)d_in[2];
  const float* outW = (const float*)d_in[3];
  const float* opB = (const float*)d_in[4];
  const float* ggW = (const float*)d_in[5];
  const float* ggB = (const float*)d_in[6];
  const float* g1 = (const float*)d_in[7];
  const float* b1 = (const float*)d_in[8];
  const float* g2 = (const float*)d_in[9];
  const float* b2 = (const float*)d_in[10];
  float* out = (float*)d_out;
  char* ws = (char*)d_ws;
  const size_t MB = 1ull << 20;
  bf16* xb = (bf16*)(ws);              // 8 MB
  bf16* qr = (bf16*)(ws + 8 * MB);     // 8 MB, dead after in-proj
  bf16* ctx = (bf16*)(ws + 8 * MB);    // overlays qr (attn output)
  bf16* wI = (bf16*)(ws + 16 * MB);    // 6 MB
  bf16* wO = (bf16*)(ws + 22 * MB);    // 2 MB
  bf16* wG = (bf16*)(ws + 24 * MB);    // 4 MB
  bf16* qk = (bf16*)(ws + 28 * MB);    // 16 MB, dead after attn
  bf16* projB = (bf16*)(ws + 28 * MB); // overlays qk
  bf16* vbT = (bf16*)(ws + 44 * MB);   // 8 MB V^T, dead after attn
  float* ao = (float*)(ws + 44 * MB);  // 16 MB f32, overlays vbT
  bf16* hB = (bf16*)(ws + 60 * MB);    // 8 MB

  rope_cast<<<NTOK * 512 / 256, 256, 0, stream>>>(x, xb, qr);
  cast_w<<<(3072 * 1024 / 4) / 256, 256, 0, stream>>>(inW, wI, 3072 * 1024);
  cast_w<<<(1024 * 1024 / 4) / 256, 256, 0, stream>>>(outW, wO, 1024 * 1024);
  cast_w<<<(2048 * 1024 / 4) / 256, 256, 0, stream>>>(ggW, wG, 2048 * 1024);
  gemm_in<<<dim3(24, 32), 256, 0, stream>>>(qr, xb, wI, inB, qk, vbT);
  attn6<<<dim3(16, 16, 2), 256, 0, stream>>>(qk, vbT, ctx);
  gemm_bt64<<<dim3(16, 32), 256, 0, stream>>>(ctx, wO, opB, ao,
                                              NTOK, 1024, 1024);
  ln1_k<<<NTOK, 256, 0, stream>>>(x, ao, g1, b1, ao, hB);
  gemm_bt<<<dim3(16, 32), 256, 0, stream>>>(hB, wG, ggB, nullptr, projB,
                                            NTOK, 2048, 1024);
  geglu_ln2<<<NTOK, 256, 0, stream>>>(ao, projB, g2, b2, out);
}

// Round 6
// 273.849 us; speedup vs baseline: 1.0761x; 1.0128x over previous
//
#include <hip/hip_runtime.h>

// TransformerBlock on MI355X (gfx950).
// Fused in-proj (q,k from RoPE(x); v from x, written transposed), 16-head
// flash attention (D=64): 32x32x16 MFMA, S^T = K·Q^T. P stays entirely in
// registers: V is stored in LDS with per-16 key-group permutation
// [0-3,8-11,4-7,12-15] so the PV A-fragment is a direct register concat of
// the S^T C-layout quads (no shuffles, no LDS round-trip). Double-buffered
// K/V with ONE barrier per tile; XCD-swizzled grid for K/V L2 reuse.
// GEMMs: bf16 MFMA 16x16x32, BK=32, global_load_lds(16B).

typedef __bf16 bf16;
typedef bf16 bf16x8 __attribute__((ext_vector_type(8)));
typedef bf16 bf16x4 __attribute__((ext_vector_type(4)));
typedef float f32x4 __attribute__((ext_vector_type(4)));
typedef float f32x16 __attribute__((ext_vector_type(16)));

#define EMB 1024
#define SEQ 2048
#define NTOK 4096
#define NH 16
#define HD 64

__device__ __forceinline__ f32x4 mfma16(bf16x8 a, bf16x8 b, f32x4 c) {
  return __builtin_amdgcn_mfma_f32_16x16x32_bf16(a, b, c, 0, 0, 0);
}
__device__ __forceinline__ f32x16 mfma32(bf16x8 a, bf16x8 b, f32x16 c) {
  return __builtin_amdgcn_mfma_f32_32x32x16_bf16(a, b, c, 0, 0, 0);
}

__device__ __forceinline__ void gll16(const void* g, void* l) {
  __builtin_amdgcn_global_load_lds(
      (const __attribute__((address_space(1))) void*)g,
      (__attribute__((address_space(3))) void*)l, 16, 0, 0);
}

__device__ __forceinline__ unsigned pk2(float a, float b) {
  union { bf16 h[2]; unsigned u; } t;
  t.h[0] = (bf16)a; t.h[1] = (bf16)b;
  return t.u;
}

// ---------------- elementwise prep ----------------

__global__ __launch_bounds__(256) void rope_cast(
    const float* __restrict__ x, bf16* __restrict__ xb, bf16* __restrict__ qr) {
  int idx = blockIdx.x * 256 + threadIdx.x;   // 0 .. NTOK*512
  int row = idx >> 9;
  int i = idx & 511;
  int h = i >> 5, d2 = i & 31;
  int pos = row & (SEQ - 1);
  int c0 = h * HD + d2;
  size_t base = (size_t)row * EMB;
  float x0 = x[base + c0], x1 = x[base + c0 + 32];
  float invf = exp2f(-(float)d2 * 0.4152410118609203f);
  float ang = (float)pos * invf;
  float sn, cs;
  sincosf(ang, &sn, &cs);
  qr[base + c0] = (bf16)(x0 * cs - x1 * sn);
  qr[base + c0 + 32] = (bf16)(x1 * cs + x0 * sn);
  xb[base + c0] = (bf16)x0;
  xb[base + c0 + 32] = (bf16)x1;
}

__global__ __launch_bounds__(256) void cast_w(
    const float* __restrict__ w, bf16* __restrict__ o, int n) {
  int i = (blockIdx.x * 256 + threadIdx.x) * 4;
  if (i < n) {
    float4 f = *(const float4*)(w + i);
    o[i] = (bf16)f.x; o[i + 1] = (bf16)f.y;
    o[i + 2] = (bf16)f.z; o[i + 3] = (bf16)f.w;
  }
}

// ---------------- fused in-proj GEMM ----------------
__global__ __launch_bounds__(256) void gemm_in(
    const bf16* __restrict__ Aq, const bf16* __restrict__ Ax,
    const bf16* __restrict__ W, const float* __restrict__ bias,
    bf16* __restrict__ qk, bf16* __restrict__ vT) {
  __shared__ bf16 As[128 * 32];
  __shared__ bf16 Bs[128 * 32];
  const int tid = threadIdx.x, lane = tid & 63, wave = tid >> 6;
  const int quad = lane >> 4, l16 = lane & 15;
  const int m0 = blockIdx.y * 128, n0 = blockIdx.x * 128;
  const bf16* A = (n0 < 2048) ? Aq : Ax;
  const int K = 1024;
  const int wm = (wave >> 1) * 64, wn = (wave & 1) * 64;
  const int srow = wave * 32 + (lane >> 2);
  const int scol = (lane & 3) * 8;
  f32x4 acc[4][4] = {};
  for (int k0 = 0; k0 < K; k0 += 32) {
    __syncthreads();
    gll16(A + (size_t)(m0 + srow) * K + k0 + scol, As + wave * 1024);
    gll16(A + (size_t)(m0 + srow + 16) * K + k0 + scol, As + wave * 1024 + 512);
    gll16(W + (size_t)(n0 + srow) * K + k0 + scol, Bs + wave * 1024);
    gll16(W + (size_t)(n0 + srow + 16) * K + k0 + scol, Bs + wave * 1024 + 512);
    __syncthreads();
    bf16x8 af[4], bw[4];
#pragma unroll
    for (int t = 0; t < 4; ++t) {
      af[t] = *(const bf16x8*)(As + (wm + t * 16 + l16) * 32 + quad * 8);
      bw[t] = *(const bf16x8*)(Bs + (wn + t * 16 + l16) * 32 + quad * 8);
    }
#pragma unroll
    for (int mt = 0; mt < 4; ++mt)
#pragma unroll
      for (int nt = 0; nt < 4; ++nt)
        acc[mt][nt] = mfma16(af[mt], bw[nt], acc[mt][nt]);
  }
  if (n0 < 2048) {
#pragma unroll
    for (int mt = 0; mt < 4; ++mt)
      for (int nt = 0; nt < 4; ++nt) {
        const int n = n0 + wn + nt * 16 + l16;
        const float bv = bias[n];
#pragma unroll
        for (int r = 0; r < 4; ++r) {
          const int m = m0 + wm + mt * 16 + quad * 4 + r;
          qk[(size_t)m * 2048 + n] = (bf16)(acc[mt][nt][r] + bv);
        }
      }
  } else {
#pragma unroll
    for (int mt = 0; mt < 4; ++mt)
      for (int nt = 0; nt < 4; ++nt) {
        const int n = n0 + wn + nt * 16 + l16;
        const float bv = bias[n];
        const int m = m0 + wm + mt * 16 + quad * 4;
        const int bb = m >> 11, s = m & 2047;
        bf16x4 pkv;
#pragma unroll
        for (int r = 0; r < 4; ++r) pkv[r] = (bf16)(acc[mt][nt][r] + bv);
        *(bf16x4*)(vT + (((size_t)bb * 1024 + (n - 2048)) << 11) + s) = pkv;
      }
  }
}

// ---------------- GEMM 128x128: C = A @ W^T + bias ----------------
__global__ __launch_bounds__(256) void gemm_bt(
    const bf16* __restrict__ A, const bf16* __restrict__ W,
    const float* __restrict__ bias,
    float* __restrict__ outF, bf16* __restrict__ outB,
    int M, int N, int K) {
  __shared__ bf16 As[128 * 32];
  __shared__ bf16 Bs[128 * 32];
  const int tid = threadIdx.x, lane = tid & 63, wave = tid >> 6;
  const int quad = lane >> 4, l16 = lane & 15;
  const int m0 = blockIdx.y * 128, n0 = blockIdx.x * 128;
  const int wm = (wave >> 1) * 64, wn = (wave & 1) * 64;
  const int srow = wave * 32 + (lane >> 2);
  const int scol = (lane & 3) * 8;
  f32x4 acc[4][4] = {};
  for (int k0 = 0; k0 < K; k0 += 32) {
    __syncthreads();
    gll16(A + (size_t)(m0 + srow) * K + k0 + scol, As + wave * 1024);
    gll16(A + (size_t)(m0 + srow + 16) * K + k0 + scol, As + wave * 1024 + 512);
    gll16(W + (size_t)(n0 + srow) * K + k0 + scol, Bs + wave * 1024);
    gll16(W + (size_t)(n0 + srow + 16) * K + k0 + scol, Bs + wave * 1024 + 512);
    __syncthreads();
    bf16x8 af[4], bw[4];
#pragma unroll
    for (int t = 0; t < 4; ++t) {
      af[t] = *(const bf16x8*)(As + (wm + t * 16 + l16) * 32 + quad * 8);
      bw[t] = *(const bf16x8*)(Bs + (wn + t * 16 + l16) * 32 + quad * 8);
    }
#pragma unroll
    for (int mt = 0; mt < 4; ++mt)
#pragma unroll
      for (int nt = 0; nt < 4; ++nt)
        acc[mt][nt] = mfma16(af[mt], bw[nt], acc[mt][nt]);
  }
#pragma unroll
  for (int mt = 0; mt < 4; ++mt)
    for (int nt = 0; nt < 4; ++nt) {
      const int n = n0 + wn + nt * 16 + l16;
      const float bv = bias ? bias[n] : 0.0f;
#pragma unroll
      for (int r = 0; r < 4; ++r) {
        const int m = m0 + wm + mt * 16 + quad * 4 + r;
        const float v = acc[mt][nt][r] + bv;
        if (outF) outF[(size_t)m * N + n] = v;
        if (outB) outB[(size_t)m * N + n] = (bf16)v;
      }
    }
}

// ---------------- GEMM 128x64 tiles ----------------
__global__ __launch_bounds__(256) void gemm_bt64(
    const bf16* __restrict__ A, const bf16* __restrict__ W,
    const float* __restrict__ bias, float* __restrict__ outF,
    int M, int N, int K) {
  __shared__ bf16 As[128 * 32];
  __shared__ bf16 Bs[64 * 32];
  const int tid = threadIdx.x, lane = tid & 63, wave = tid >> 6;
  const int quad = lane >> 4, l16 = lane & 15;
  const int m0 = blockIdx.y * 128, n0 = blockIdx.x * 64;
  const int wm = (wave >> 1) * 64, wn = (wave & 1) * 32;
  const int srow = wave * 32 + (lane >> 2);
  const int srowB = wave * 16 + (lane >> 2);
  const int scol = (lane & 3) * 8;
  f32x4 acc[4][2] = {};
  for (int k0 = 0; k0 < K; k0 += 32) {
    __syncthreads();
    gll16(A + (size_t)(m0 + srow) * K + k0 + scol, As + wave * 1024);
    gll16(A + (size_t)(m0 + srow + 16) * K + k0 + scol, As + wave * 1024 + 512);
    gll16(W + (size_t)(n0 + srowB) * K + k0 + scol, Bs + wave * 512);
    __syncthreads();
    bf16x8 af[4], bw[2];
#pragma unroll
    for (int t = 0; t < 4; ++t)
      af[t] = *(const bf16x8*)(As + (wm + t * 16 + l16) * 32 + quad * 8);
#pragma unroll
    for (int t = 0; t < 2; ++t)
      bw[t] = *(const bf16x8*)(Bs + (wn + t * 16 + l16) * 32 + quad * 8);
#pragma unroll
    for (int mt = 0; mt < 4; ++mt)
#pragma unroll
      for (int nt = 0; nt < 2; ++nt)
        acc[mt][nt] = mfma16(af[mt], bw[nt], acc[mt][nt]);
  }
#pragma unroll
  for (int mt = 0; mt < 4; ++mt)
    for (int nt = 0; nt < 2; ++nt) {
      const int n = n0 + wn + nt * 16 + l16;
      const float bv = bias[n];
#pragma unroll
      for (int r = 0; r < 4; ++r) {
        const int m = m0 + wm + mt * 16 + quad * 4 + r;
        outF[(size_t)m * N + n] = acc[mt][nt][r] + bv;
      }
    }
}

// ---------------- flash attention v7 ----------------
// 512 blocks (XCD-swizzled 1D grid), 4 waves x 32 q-rows, 32x32x16 MFMA.
// S^T = K·Q^T. V stored in LDS with per-16 key-group column permutation
// [0-3,8-11,4-7,12-15]: PV A-frag = u[4kk..4kk+3] directly (no shuffles).
// Double-buffered K/V, ONE __syncthreads per 64-key tile.
__global__ __launch_bounds__(256) void attn7(
    const bf16* __restrict__ QK, const bf16* __restrict__ VT,
    bf16* __restrict__ ctx) {
  __shared__ __align__(16) bf16 Ks[2][64 * 64];
  __shared__ __align__(16) bf16 Vs[2][64 * 64];
  __shared__ float Linv[4][32];
  const int tid = threadIdx.x, lane = tid & 63, wave = tid >> 6;
  const int hi = lane >> 5, l31 = lane & 31, l7 = lane & 7;
  // XCD swizzle: all 16 q-tiles of one (b,h) -> same XCD (bid%8 heuristic)
  const int bid = blockIdx.x;
  const int hb = (bid & 7) * 4 + ((bid >> 3) & 3);
  const int qt = bid >> 5;
  const int h = hb & 15, b = hb >> 4;

  // Q B-frags (lane owns col q=l31, k=d=t*16+hi*8+j), pre-scaled by 0.125
  bf16x8 qf[4];
  {
    const int qrow = qt * 128 + wave * 32 + l31;
    const bf16* qp = QK + (size_t)(b * SEQ + qrow) * 2048 + h * HD + hi * 8;
#pragma unroll
    for (int t = 0; t < 4; ++t) {
      bf16x8 v = *(const bf16x8*)(qp + t * 16);
#pragma unroll
      for (int j = 0; j < 8; ++j) v[j] = (bf16)((float)v[j] * 0.125f);
      qf[t] = v;
    }
  }
  f32x16 o0 = {}, o1 = {};
  float lpart = 0.0f;

  const int srow = tid >> 3;   // 0..31 (d for V, key-row for K)
  const int sc16 = tid & 7;    // 16B chunk
  const bf16* kg = QK + (size_t)(b * SEQ) * 2048 + 1024 + h * HD + sc16 * 8;
  const bf16* vg = VT + ((size_t)(b * NH + h) * HD) * 2048 + sc16 * 8;
  // V write positions (permuted): lo quad -> g4lo, hi quad -> g4lo+2
  const int g4lo = 2 * sc16 - (sc16 & 1);

  bf16x8 kcur[2], vcur[2];
#pragma unroll
  for (int p = 0; p < 2; ++p) {   // tile 0
    const int row = p * 32 + srow;
    kcur[p] = *(const bf16x8*)(kg + (size_t)row * 2048);
    vcur[p] = *(const bf16x8*)(vg + (size_t)row * 2048);
  }
  // stage tile 0 into buf 0
#pragma unroll
  for (int p = 0; p < 2; ++p) {
    const int row = p * 32 + srow;
    const int m2 = (row & 7) << 1;
    *(bf16x8*)(Ks[0] + row * 64 + ((sc16 ^ (row & 7)) * 8)) = kcur[p];
    union { bf16x8 v; unsigned long long q[2]; } u2;
    u2.v = vcur[p];
    *(unsigned long long*)(Vs[0] + row * 64 + ((g4lo ^ m2) * 4)) = u2.q[0];
    *(unsigned long long*)(Vs[0] + row * 64 + (((g4lo + 2) ^ m2) * 4)) = u2.q[1];
  }
#pragma unroll
  for (int p = 0; p < 2; ++p) {   // prefetch tile 1
    const int row = p * 32 + srow;
    kcur[p] = *(const bf16x8*)(kg + (size_t)(64 + row) * 2048);
    vcur[p] = *(const bf16x8*)(vg + (size_t)row * 2048 + 64);
  }

  for (int t = 0; t < 32; ++t) {
    __syncthreads();   // buf[t&1] fully staged; prior readers of buf[(t+1)&1] done
    const bf16* ks = Ks[t & 1];
    const bf16* vs = Vs[t & 1];
    if (t + 1 < 32) {
      bf16* kd = Ks[(t + 1) & 1];
      bf16* vd = Vs[(t + 1) & 1];
#pragma unroll
      for (int p = 0; p < 2; ++p) {
        const int row = p * 32 + srow;
        const int m2 = (row & 7) << 1;
        *(bf16x8*)(kd + row * 64 + ((sc16 ^ (row & 7)) * 8)) = kcur[p];
        union { bf16x8 v; unsigned long long q[2]; } u2;
        u2.v = vcur[p];
        *(unsigned long long*)(vd + row * 64 + ((g4lo ^ m2) * 4)) = u2.q[0];
        *(unsigned long long*)(vd + row * 64 + (((g4lo + 2) ^ m2) * 4)) = u2.q[1];
      }
      if (t + 2 < 32) {
        const int kb2 = (t + 2) * 64;
#pragma unroll
        for (int p = 0; p < 2; ++p) {
          const int row = p * 32 + srow;
          kcur[p] = *(const bf16x8*)(kg + (size_t)(kb2 + row) * 2048);
          vcur[p] = *(const bf16x8*)(vg + (size_t)row * 2048 + kb2);
        }
      }
    }
    // S^T[key][q]
    f32x16 s0 = {}, s1 = {};
#pragma unroll
    for (int tt = 0; tt < 4; ++tt) {
      const int swc = ((tt * 2 + hi) ^ l7) * 8;
      bf16x8 k0 = *(const bf16x8*)(ks + l31 * 64 + swc);
      bf16x8 k1 = *(const bf16x8*)(ks + (32 + l31) * 64 + swc);
      s0 = mfma32(k0, qf[tt], s0);
      s1 = mfma32(k1, qf[tt], s1);
    }
    // exp -> u[2g],u[2g+1] = quad g = keys 8g+4hi+{0..3}
    unsigned u[16];
#pragma unroll
    for (int g = 0; g < 8; ++g) {
      const int base = (g & 3) * 4;
      float e0, e1, e2, e3;
      if (g < 4) {
        e0 = __expf(s0[base]); e1 = __expf(s0[base + 1]);
        e2 = __expf(s0[base + 2]); e3 = __expf(s0[base + 3]);
      } else {
        e0 = __expf(s1[base]); e1 = __expf(s1[base + 1]);
        e2 = __expf(s1[base + 2]); e3 = __expf(s1[base + 3]);
      }
      lpart += (e0 + e1) + (e2 + e3);
      u[g * 2] = pk2(e0, e1);
      u[g * 2 + 1] = pk2(e2, e3);
    }
    // PV: A-frag = u[4kk..4kk+3] directly (V key-columns permuted in LDS)
#pragma unroll
    for (int kk = 0; kk < 4; ++kk) {
      union { unsigned w[4]; bf16x8 v; } fw;
      fw.w[0] = u[4 * kk]; fw.w[1] = u[4 * kk + 1];
      fw.w[2] = u[4 * kk + 2]; fw.w[3] = u[4 * kk + 3];
      const int swz = (4 * kk + 2 * hi) ^ (l7 << 1);
      bf16x8 v0 = *(const bf16x8*)(vs + l31 * 64 + swz * 4);
      bf16x8 v1 = *(const bf16x8*)(vs + (32 + l31) * 64 + swz * 4);
      o0 = mfma32(fw.v, v0, o0);
      o1 = mfma32(fw.v, v1, o1);
    }
  }
  // epilogue
  float ltot = lpart + __shfl_xor(lpart, 32, 64);
  if (lane < 32) Linv[wave][lane] = 1.0f / ltot;
#pragma unroll
  for (int r = 0; r < 16; ++r) {
    const int qloc = (r & 3) + 8 * (r >> 2) + 4 * hi;
    const float inv = Linv[wave][qloc];
    const int qrow = qt * 128 + wave * 32 + qloc;
    bf16* cp = ctx + (size_t)(b * SEQ + qrow) * EMB + h * HD;
    cp[l31] = (bf16)(o0[r] * inv);
    cp[32 + l31] = (bf16)(o1[r] * inv);
  }
}

// ---------------- residual + LayerNorm ----------------
__global__ __launch_bounds__(256) void ln1_k(
    const float* __restrict__ x, const float* __restrict__ ao,
    const float* __restrict__ g, const float* __restrict__ bta,
    float* __restrict__ hF, bf16* __restrict__ hB) {
  int row = blockIdx.x, tid = threadIdx.x;
  const float* xr = x + (size_t)row * EMB;
  const float* ar = ao + (size_t)row * EMB;
  float v[4], s = 0.0f, s2 = 0.0f;
#pragma unroll
  for (int i = 0; i < 4; ++i) {
    float t = xr[tid + i * 256] + ar[tid + i * 256];
    v[i] = t; s += t; s2 += t * t;
  }
#pragma unroll
  for (int off = 1; off < 64; off <<= 1) {
    s += __shfl_xor(s, off, 64);
    s2 += __shfl_xor(s2, off, 64);
  }
  __shared__ float red[8];
  int wave = tid >> 6, lane = tid & 63;
  if (lane == 0) { red[wave] = s; red[4 + wave] = s2; }
  __syncthreads();
  s = red[0] + red[1] + red[2] + red[3];
  s2 = red[4] + red[5] + red[6] + red[7];
  float mean = s * (1.0f / EMB);
  float var = s2 * (1.0f / EMB) - mean * mean;
  float inv = rsqrtf(var + 1e-5f);
#pragma unroll
  for (int i = 0; i < 4; ++i) {
    int c = tid + i * 256;
    float t = (v[i] - mean) * inv * g[c] + bta[c];
    hF[(size_t)row * EMB + c] = t;
    hB[(size_t)row * EMB + c] = (bf16)t;
  }
}

__global__ __launch_bounds__(256) void geglu_ln2(
    const float* __restrict__ h, const bf16* __restrict__ proj,
    const float* __restrict__ g, const float* __restrict__ bta,
    float* __restrict__ out) {
  int row = blockIdx.x, tid = threadIdx.x;
  const float* hr = h + (size_t)row * EMB;
  const bf16* pr = proj + (size_t)row * 2048;
  float v[4], s = 0.0f, s2 = 0.0f;
#pragma unroll
  for (int i = 0; i < 4; ++i) {
    int c = tid + i * 256;
    float val = (float)pr[c];
    float gate = (float)pr[1024 + c];
    float ge = 0.5f * gate * (1.0f + erff(gate * 0.70710678f));
    float t = hr[c] + val * ge;
    v[i] = t; s += t; s2 += t * t;
  }
#pragma unroll
  for (int off = 1; off < 64; off <<= 1) {
    s += __shfl_xor(s, off, 64);
    s2 += __shfl_xor(s2, off, 64);
  }
  __shared__ float red[8];
  int wave = tid >> 6, lane = tid & 63;
  if (lane == 0) { red[wave] = s; red[4 + wave] = s2; }
  __syncthreads();
  s = red[0] + red[1] + red[2] + red[3];
  s2 = red[4] + red[5] + red[6] + red[7];
  float mean = s * (1.0f / EMB);
  float var = s2 * (1.0f / EMB) - mean * mean;
  float inv = rsqrtf(var + 1e-5f);
#pragma unroll
  for (int i = 0; i < 4; ++i) {
    int c = tid + i * 256;
    out[(size_t)row * EMB + c] = (v[i] - mean) * inv * g[c] + bta[c];
  }
}

extern "C" void kernel_launch(void* const* d_in, const int* in_sizes, int n_in,
                              void* d_out, int out_size, void* d_ws, size_t ws_size,
                              hipStream_t stream) {
  const float* x = (const float*)d_in[0];
  const float* inW = (const float*)d_in[1];
  const float* inB = (const float*)d_in[2];
  const float* outW = (const float*)d_in[3];
  const float* opB = (const float*)d_in[4];
  const float* ggW = (const float*)d_in[5];
  const float* ggB = (const float*)d_in[6];
  const float* g1 = (const float*)d_in[7];
  const float* b1 = (const float*)d_in[8];
  const float* g2 = (const float*)d_in[9];
  const float* b2 = (const float*)d_in[10];
  float* out = (float*)d_out;
  char* ws = (char*)d_ws;
  const size_t MB = 1ull << 20;
  bf16* xb = (bf16*)(ws);              // 8 MB
  bf16* qr = (bf16*)(ws + 8 * MB);     // 8 MB, dead after in-proj
  bf16* ctx = (bf16*)(ws + 8 * MB);    // overlays qr (attn output)
  bf16* wI = (bf16*)(ws + 16 * MB);    // 6 MB
  bf16* wO = (bf16*)(ws + 22 * MB);    // 2 MB
  bf16* wG = (bf16*)(ws + 24 * MB);    // 4 MB
  bf16* qk = (bf16*)(ws + 28 * MB);    // 16 MB, dead after attn
  bf16* projB = (bf16*)(ws + 28 * MB); // overlays qk
  bf16* vbT = (bf16*)(ws + 44 * MB);   // 8 MB V^T, dead after attn
  float* ao = (float*)(ws + 44 * MB);  // 16 MB f32, overlays vbT
  bf16* hB = (bf16*)(ws + 60 * MB);    // 8 MB

  rope_cast<<<NTOK * 512 / 256, 256, 0, stream>>>(x, xb, qr);
  cast_w<<<(3072 * 1024 / 4) / 256, 256, 0, stream>>>(inW, wI, 3072 * 1024);
  cast_w<<<(1024 * 1024 / 4) / 256, 256, 0, stream>>>(outW, wO, 1024 * 1024);
  cast_w<<<(2048 * 1024 / 4) / 256, 256, 0, stream>>>(ggW, wG, 2048 * 1024);
  gemm_in<<<dim3(24, 32), 256, 0, stream>>>(qr, xb, wI, inB, qk, vbT);
  attn7<<<512, 256, 0, stream>>>(qk, vbT, ctx);
  gemm_bt64<<<dim3(16, 32), 256, 0, stream>>>(ctx, wO, opB, ao,
                                              NTOK, 1024, 1024);
  ln1_k<<<NTOK, 256, 0, stream>>>(x, ao, g1, b1, ao, hB);
  gemm_bt<<<dim3(16, 32), 256, 0, stream>>>(hB, wG, ggB, nullptr, projB,
                                            NTOK, 2048, 1024);
  geglu_ln2<<<NTOK, 256, 0, stream>>>(ao, projB, g2, b2, out);
}